// Round 1
// baseline (1491.671 us; speedup 1.0000x reference)
//
#include <hip/hip_runtime.h>

#define NN 50000
#define EE 800000
#define ETOT (EE + NN)
#define IN_DIM 128
#define EDGE_DIM 32
#define EMB 256
#define HH 8
#define CC 32
#define LL 4
#define NEG_SLOPE 0.2f

// ---------------- small utility kernels ----------------

__global__ void zero_int_kernel(int* p, int n) {
    int i = blockIdx.x * 256 + threadIdx.x;
    if (i < n) p[i] = 0;
}

// mean of edge_attr over E rows -> accum[32] (atomic partial sums)
__global__ __launch_bounds__(256) void mean_kernel(const float* __restrict__ ea,
                                                   float* __restrict__ accum) {
    __shared__ float part[256];
    int d = threadIdx.x & 31;
    int g = threadIdx.x >> 5;  // 8 edge-groups per block
    float s = 0.f;
    for (int e = blockIdx.x * 8 + g; e < EE; e += gridDim.x * 8)
        s += ea[(size_t)e * 32 + d];
    part[threadIdx.x] = s;
    __syncthreads();
    if (g == 0) {
        float t = part[d];
        for (int k = 1; k < 8; ++k) t += part[k * 32 + d];
        atomicAdd(&accum[d], t);
    }
}

// finalize mean_ea; compute v[l][d][h] = sum_c We[l][d][h*32+c]*att_edge[l][h][c]
__global__ void precompute_kernel(const float* __restrict__ accum,
                                  const float* __restrict__ We,
                                  const float* __restrict__ att_e,
                                  float* __restrict__ mean_ea,
                                  float* __restrict__ v) {
    int t = threadIdx.x;  // 1024 threads
    if (t < 32) mean_ea[t] = accum[t] * (1.0f / EE);
    int l = t >> 8, rem = t & 255, d = rem >> 3, hh = rem & 7;
    float s = 0.f;
#pragma unroll
    for (int c = 0; c < 32; ++c)
        s += We[((size_t)(l * 32 + d)) * 256 + hh * 32 + c] * att_e[l * 256 + hh * 32 + c];
    v[t] = s;  // layout v[l*256 + d*8 + h]
}

__global__ void hist_kernel(const int* __restrict__ ei, int* __restrict__ cnt) {
    int i = blockIdx.x * 256 + threadIdx.x;
    if (i >= ETOT) return;
    int dst = (i < EE) ? ei[EE + i] : (i - EE);
    atomicAdd(&cnt[dst], 1);
}

// single-block exclusive scan of cnt[0..NN) -> row_ptr[0..NN], copy to fill
__global__ __launch_bounds__(1024) void scan_kernel(const int* __restrict__ cnt,
                                                    int* __restrict__ row_ptr,
                                                    int* __restrict__ fill) {
    __shared__ int sbuf[1024];
    int t = threadIdx.x;
    int carry = 0;
    for (int base = 0; base < NN; base += 1024) {
        int i = base + t;
        int x = (i < NN) ? cnt[i] : 0;
        __syncthreads();
        sbuf[t] = x;
        __syncthreads();
        for (int off = 1; off < 1024; off <<= 1) {
            int add = (t >= off) ? sbuf[t - off] : 0;
            __syncthreads();
            sbuf[t] += add;
            __syncthreads();
        }
        int incl = sbuf[t];
        if (i < NN) {
            int excl = carry + incl - x;
            row_ptr[i] = excl;
            fill[i] = excl;
        }
        carry += sbuf[1023];
    }
    if (t == 0) row_ptr[NN] = carry;
}

__global__ void scatter_kernel(const int* __restrict__ ei, int* __restrict__ fill,
                               int* __restrict__ sorted_src, int* __restrict__ sorted_eid) {
    int i = blockIdx.x * 256 + threadIdx.x;
    if (i >= ETOT) return;
    int dst, src;
    if (i < EE) { src = ei[i]; dst = ei[EE + i]; }
    else        { src = i - EE; dst = i - EE; }
    int pos = atomicAdd(&fill[dst], 1);
    sorted_src[pos] = src;
    sorted_eid[pos] = i;
}

// ---------------- f32 tiled GEMM: C[M,N] = A[M,K]@B[K,N] (+bias) ----------------
__global__ __launch_bounds__(256) void gemm_f32(const float* __restrict__ A,
                                                const float* __restrict__ B,
                                                const float* __restrict__ bias,
                                                float* __restrict__ C,
                                                int M, int K, int N) {
    __shared__ float As[16][68];  // [k][m], padded
    __shared__ float Bs[16][64];  // [k][n]
    int tid = threadIdx.x;
    int tx = tid & 15, ty = tid >> 4;
    int m0 = blockIdx.x * 64;
    int n0 = blockIdx.y * 64;
    int la_k = tid & 15, la_m = tid >> 4;
    int lb_n = tid & 63, lb_k = tid >> 6;
    float acc[4][4] = {};
    for (int k0 = 0; k0 < K; k0 += 16) {
#pragma unroll
        for (int r = 0; r < 4; ++r) {
            int m = m0 + la_m + r * 16;
            As[la_k][la_m + r * 16] = (m < M) ? A[(size_t)m * K + k0 + la_k] : 0.f;
        }
#pragma unroll
        for (int r = 0; r < 4; ++r)
            Bs[lb_k + r * 4][lb_n] = B[(size_t)(k0 + lb_k + r * 4) * N + n0 + lb_n];
        __syncthreads();
#pragma unroll
        for (int kk = 0; kk < 16; ++kk) {
            float4 a4 = *(const float4*)&As[kk][ty * 4];
            float4 b4 = *(const float4*)&Bs[kk][tx * 4];
            float a[4] = {a4.x, a4.y, a4.z, a4.w};
            float b[4] = {b4.x, b4.y, b4.z, b4.w};
#pragma unroll
            for (int i = 0; i < 4; ++i)
#pragma unroll
                for (int j = 0; j < 4; ++j) acc[i][j] += a[i] * b[j];
        }
        __syncthreads();
    }
    float4 bb = {0.f, 0.f, 0.f, 0.f};
    if (bias) bb = *(const float4*)&bias[n0 + tx * 4];
#pragma unroll
    for (int i = 0; i < 4; ++i) {
        int m = m0 + ty * 4 + i;
        if (m < M) {
            float4 o;
            o.x = acc[i][0] + bb.x;
            o.y = acc[i][1] + bb.y;
            o.z = acc[i][2] + bb.z;
            o.w = acc[i][3] + bb.w;
            *(float4*)&C[(size_t)m * N + n0 + tx * 4] = o;
        }
    }
}

// ---------------- per-layer kernels ----------------

// a_s[n,h], a_d[n,h] from hp
__global__ __launch_bounds__(256) void a_sd_kernel(const float* __restrict__ hp,
                                                   const float* __restrict__ att_s,
                                                   const float* __restrict__ att_d,
                                                   float* __restrict__ a_s,
                                                   float* __restrict__ a_d) {
    int idx = blockIdx.x * 256 + threadIdx.x;
    if (idx >= NN * 8) return;
    int n = idx >> 3, hh = idx & 7;
    const float* base = hp + (size_t)n * 256 + hh * 32;
    const float* as = att_s + hh * 32;
    const float* ad = att_d + hh * 32;
    float ss = 0.f, sd = 0.f;
#pragma unroll
    for (int c = 0; c < 32; ++c) {
        float vv = base[c];
        ss += vv * as[c];
        sd += vv * ad[c];
    }
    a_s[idx] = ss;
    a_d[idx] = sd;
}

// e_edge[p][h] for sorted edge positions, layer slice of v
__global__ __launch_bounds__(256) void e_edge_kernel(const float* __restrict__ edge_attr,
                                                     const float* __restrict__ mean_ea,
                                                     const int* __restrict__ sorted_eid,
                                                     const float* __restrict__ v,  // +l*256
                                                     float* __restrict__ e_edge) {
    __shared__ float vs[256];
    vs[threadIdx.x] = v[threadIdx.x];
    __syncthreads();
    int p = blockIdx.x * 256 + threadIdx.x;
    if (p >= ETOT) return;
    int eid = sorted_eid[p];
    const float* row = (eid < EE) ? (edge_attr + (size_t)eid * 32) : mean_ea;
    float acc[8] = {};
#pragma unroll
    for (int d = 0; d < 32; ++d) {
        float rv = row[d];
#pragma unroll
        for (int h = 0; h < 8; ++h) acc[h] += rv * vs[d * 8 + h];
    }
#pragma unroll
    for (int h = 0; h < 8; ++h) e_edge[(size_t)p * 8 + h] = acc[h];
}

// one wave per dst node: segment softmax + weighted gather-sum, no atomics
__global__ __launch_bounds__(256) void aggregate_kernel(const float* __restrict__ hp,
                                                        const float* __restrict__ a_s,
                                                        const float* __restrict__ a_d,
                                                        const float* __restrict__ e_edge,
                                                        const int* __restrict__ sorted_src,
                                                        const int* __restrict__ row_ptr,
                                                        const float* __restrict__ bias,  // +l*256
                                                        float* __restrict__ hnew) {
    int n = (blockIdx.x * 256 + threadIdx.x) >> 6;
    if (n >= NN) return;
    int lane = threadIdx.x & 63;
    int beg = row_ptr[n], end = row_ptr[n + 1];

    // phase 1: lane = (edge j within chunk)*8 + head; online max+sum per head
    int h1 = lane & 7;
    float ad1 = a_d[n * 8 + h1];
    float m = -1e30f, s = 0.f;
    for (int base = beg; base < end; base += 8) {
        int j = base + (lane >> 3);
        float e = -1e30f;
        bool valid = (j < end);
        if (valid) {
            int src = sorted_src[j];
            e = a_s[src * 8 + h1] + ad1 + e_edge[(size_t)j * 8 + h1];
            e = (e >= 0.f) ? e : NEG_SLOPE * e;
        }
        float nm = fmaxf(m, e);
        s = s * __expf(m - nm) + (valid ? __expf(e - nm) : 0.f);
        m = nm;
    }
    // reduce over the 8 edge-slots (lane bits 3..5)
    for (int off = 8; off < 64; off <<= 1) {
        float mo = __shfl_xor(m, off);
        float so = __shfl_xor(s, off);
        float nm = fmaxf(m, mo);
        s = s * __expf(m - nm) + so * __expf(mo - nm);
        m = nm;
    }
    // phase 2: lane = head*8 + channel-group; accumulate alpha * hp[src]
    int h2 = lane >> 3;
    float mh = __shfl(m, h2);
    float sh = __shfl(s, h2);
    float inv = 1.0f / (sh + 1e-16f);
    float ad2 = a_d[n * 8 + h2];
    float acc0 = 0.f, acc1 = 0.f, acc2 = 0.f, acc3 = 0.f;
    for (int j = beg; j < end; ++j) {
        int src = sorted_src[j];
        float e = a_s[src * 8 + h2] + ad2 + e_edge[(size_t)j * 8 + h2];
        e = (e >= 0.f) ? e : NEG_SLOPE * e;
        float alpha = __expf(e - mh) * inv;
        const float4 hv = *(const float4*)&hp[(size_t)src * 256 + lane * 4];
        acc0 += alpha * hv.x;
        acc1 += alpha * hv.y;
        acc2 += alpha * hv.z;
        acc3 += alpha * hv.w;
    }
    float4 b4 = *(const float4*)&bias[lane * 4];
    float4 o = {acc0 + b4.x, acc1 + b4.y, acc2 + b4.z, acc3 + b4.w};
    *(float4*)&hnew[(size_t)n * 256 + lane * 4] = o;
}

// out[n] = dot(h[n,:], w_out) + b_out
__global__ __launch_bounds__(256) void out_kernel(const float* __restrict__ h,
                                                  const float* __restrict__ w_out,
                                                  const float* __restrict__ b_out,
                                                  float* __restrict__ out) {
    int n = (blockIdx.x * 256 + threadIdx.x) >> 6;
    if (n >= NN) return;
    int lane = threadIdx.x & 63;
    const float4 hv = *(const float4*)&h[(size_t)n * 256 + lane * 4];
    const float4 wv = *(const float4*)&w_out[lane * 4];
    float s = hv.x * wv.x + hv.y * wv.y + hv.z * wv.z + hv.w * wv.w;
    for (int off = 1; off < 64; off <<= 1) s += __shfl_xor(s, off);
    if (lane == 0) out[n] = s + b_out[0];
}

// ---------------- launch ----------------

extern "C" void kernel_launch(void* const* d_in, const int* in_sizes, int n_in,
                              void* d_out, int out_size, void* d_ws, size_t ws_size,
                              hipStream_t stream) {
    const float* x         = (const float*)d_in[0];
    const int*   edge_idx  = (const int*)d_in[1];
    const float* edge_attr = (const float*)d_in[2];
    const float* w_in      = (const float*)d_in[3];
    const float* b_in      = (const float*)d_in[4];
    const float* W_l       = (const float*)d_in[5];
    const float* We_l      = (const float*)d_in[6];
    const float* att_src   = (const float*)d_in[7];
    const float* att_dst   = (const float*)d_in[8];
    const float* att_edge  = (const float*)d_in[9];
    const float* bias_l    = (const float*)d_in[10];
    const float* w_out     = (const float*)d_in[11];
    const float* b_out     = (const float*)d_in[12];
    float* out = (float*)d_out;

    char* ws = (char*)d_ws;
    size_t off = 0;
    auto alloc = [&](size_t bytes) -> void* {
        void* p = ws + off;
        off = (off + bytes + 255) & ~(size_t)255;
        return p;
    };
    float* h          = (float*)alloc((size_t)NN * EMB * 4);
    float* hp         = (float*)alloc((size_t)NN * EMB * 4);
    float* a_s        = (float*)alloc((size_t)NN * HH * 4);
    float* a_d        = (float*)alloc((size_t)NN * HH * 4);
    float* e_edge     = (float*)alloc((size_t)ETOT * HH * 4);
    int*   sorted_src = (int*)alloc((size_t)ETOT * 4);
    int*   sorted_eid = (int*)alloc((size_t)ETOT * 4);
    int*   row_ptr    = (int*)alloc((size_t)(NN + 1) * 4);
    int*   fill       = (int*)alloc((size_t)NN * 4);
    int*   cnt        = (int*)alloc((size_t)NN * 4);
    float* mean_accum = (float*)alloc(32 * 4);
    float* mean_ea    = (float*)alloc(32 * 4);
    float* v          = (float*)alloc(1024 * 4);

    // graph build (layer-invariant)
    zero_int_kernel<<<(NN + 255) / 256, 256, 0, stream>>>(cnt, NN);
    zero_int_kernel<<<1, 256, 0, stream>>>((int*)mean_accum, 32);
    mean_kernel<<<512, 256, 0, stream>>>(edge_attr, mean_accum);
    precompute_kernel<<<1, 1024, 0, stream>>>(mean_accum, We_l, att_edge, mean_ea, v);
    hist_kernel<<<(ETOT + 255) / 256, 256, 0, stream>>>(edge_idx, cnt);
    scan_kernel<<<1, 1024, 0, stream>>>(cnt, row_ptr, fill);
    scatter_kernel<<<(ETOT + 255) / 256, 256, 0, stream>>>(edge_idx, fill, sorted_src, sorted_eid);

    // input projection: h = x @ w_in + b_in
    gemm_f32<<<dim3((NN + 63) / 64, EMB / 64), 256, 0, stream>>>(x, w_in, b_in, h, NN, IN_DIM, EMB);

    for (int l = 0; l < LL; ++l) {
        gemm_f32<<<dim3((NN + 63) / 64, EMB / 64), 256, 0, stream>>>(
            h, W_l + (size_t)l * EMB * EMB, nullptr, hp, NN, EMB, EMB);
        a_sd_kernel<<<(NN * 8 + 255) / 256, 256, 0, stream>>>(
            hp, att_src + l * 256, att_dst + l * 256, a_s, a_d);
        e_edge_kernel<<<(ETOT + 255) / 256, 256, 0, stream>>>(
            edge_attr, mean_ea, sorted_eid, v + l * 256, e_edge);
        aggregate_kernel<<<NN / 4, 256, 0, stream>>>(
            hp, a_s, a_d, e_edge, sorted_src, row_ptr, bias_l + l * 256, h);
    }

    out_kernel<<<NN / 4, 256, 0, stream>>>(h, w_out, b_out, out);
}

// Round 2
// 1290.055 us; speedup vs baseline: 1.1563x; 1.1563x over previous
//
#include <hip/hip_runtime.h>

#define NN 50000
#define EE 800000
#define ETOT (EE + NN)
#define IN_DIM 128
#define EDGE_DIM 32
#define EMB 256
#define HH 8
#define CC 32
#define LL 4
#define NEG_SLOPE 0.2f

typedef __attribute__((ext_vector_type(8))) short bf16x8;
typedef __attribute__((ext_vector_type(4))) float f32x4;

__device__ inline ushort f2bf_rn(float x) {
    union { float f; uint u; } v; v.f = x;
    uint r = v.u + 0x7FFFu + ((v.u >> 16) & 1u);
    return (ushort)(r >> 16);
}
__device__ inline float bf2f(ushort b) {
    union { uint u; float f; } v; v.u = ((uint)b) << 16;
    return v.f;
}

// ---------------- small utility kernels ----------------

__global__ void zero_int_kernel(int* p, int n) {
    int i = blockIdx.x * 256 + threadIdx.x;
    if (i < n) p[i] = 0;
}

__global__ __launch_bounds__(256) void mean_kernel(const float* __restrict__ ea,
                                                   float* __restrict__ accum) {
    __shared__ float part[256];
    int d = threadIdx.x & 31;
    int g = threadIdx.x >> 5;
    float s = 0.f;
    for (int e = blockIdx.x * 8 + g; e < EE; e += gridDim.x * 8)
        s += ea[(size_t)e * 32 + d];
    part[threadIdx.x] = s;
    __syncthreads();
    if (g == 0) {
        float t = part[d];
        for (int k = 1; k < 8; ++k) t += part[k * 32 + d];
        atomicAdd(&accum[d], t);
    }
}

// finalize mean_ea; v[l][d][h] = sum_c We[l][d][h*32+c]*att_edge[l][h][c]
__global__ void precompute_kernel(const float* __restrict__ accum,
                                  const float* __restrict__ We,
                                  const float* __restrict__ att_e,
                                  float* __restrict__ mean_ea,
                                  float* __restrict__ v) {
    int t = threadIdx.x;  // 1024 threads
    if (t < 32) mean_ea[t] = accum[t] * (1.0f / EE);
    int l = t >> 8, rem = t & 255, d = rem >> 3, hh = rem & 7;
    float s = 0.f;
#pragma unroll
    for (int c = 0; c < 32; ++c)
        s += We[((size_t)(l * 32 + d)) * 256 + hh * 32 + c] * att_e[l * 256 + hh * 32 + c];
    v[t] = s;  // v[l*256 + d*8 + h]
}

__global__ void hist_kernel(const int* __restrict__ ei, int* __restrict__ cnt) {
    int i = blockIdx.x * 256 + threadIdx.x;
    if (i >= ETOT) return;
    int dst = (i < EE) ? ei[EE + i] : (i - EE);
    atomicAdd(&cnt[dst], 1);
}

__global__ __launch_bounds__(1024) void scan_kernel(const int* __restrict__ cnt,
                                                    int* __restrict__ row_ptr,
                                                    int* __restrict__ fill) {
    __shared__ int sbuf[1024];
    int t = threadIdx.x;
    int carry = 0;
    for (int base = 0; base < NN; base += 1024) {
        int i = base + t;
        int x = (i < NN) ? cnt[i] : 0;
        __syncthreads();
        sbuf[t] = x;
        __syncthreads();
        for (int off = 1; off < 1024; off <<= 1) {
            int add = (t >= off) ? sbuf[t - off] : 0;
            __syncthreads();
            sbuf[t] += add;
            __syncthreads();
        }
        int incl = sbuf[t];
        if (i < NN) {
            int excl = carry + incl - x;
            row_ptr[i] = excl;
            fill[i] = excl;
        }
        carry += sbuf[1023];
    }
    if (t == 0) row_ptr[NN] = carry;
}

__global__ void scatter_kernel(const int* __restrict__ ei, int* __restrict__ fill,
                               int* __restrict__ sorted_src, int* __restrict__ sorted_eid) {
    int i = blockIdx.x * 256 + threadIdx.x;
    if (i >= ETOT) return;
    int dst, src;
    if (i < EE) { src = ei[i]; dst = ei[EE + i]; }
    else        { src = i - EE; dst = i - EE; }
    int pos = atomicAdd(&fill[dst], 1);
    sorted_src[pos] = src;
    sorted_eid[pos] = i;
}

// split weights into transposed [n][k] bf16 hi/lo panels
// layout: mat0 (w_in): rows n=0..255, K=128, at offset 0 (32768 elems)
//         mat 1+l (W_l): K=256, at offset 32768 + l*65536
__global__ __launch_bounds__(256) void split_weights(const float* __restrict__ w_in,
                                                     const float* __restrict__ W_l,
                                                     ushort* __restrict__ bh,
                                                     ushort* __restrict__ bl) {
    int t = blockIdx.x * 256 + threadIdx.x;
    if (t >= 32768 + 4 * 65536) return;
    float val;
    size_t dst;
    if (t < 32768) {
        int n = t >> 7, k = t & 127;
        val = w_in[(size_t)k * 256 + n];
        dst = (size_t)n * 128 + k;
    } else {
        int u = t - 32768;
        int l = u >> 16, r = u & 65535;
        int n = r >> 8, k = r & 255;
        val = W_l[(size_t)l * 65536 + (size_t)k * 256 + n];
        dst = 32768 + (size_t)l * 65536 + (size_t)n * 256 + k;
    }
    ushort hi = f2bf_rn(val);
    bh[dst] = hi;
    bl[dst] = f2bf_rn(val - bf2f(hi));
}

// ---------------- MFMA GEMM: C[M,256] = A[M,K](f32) @ B[K,256] ----------------
// B given pre-split/transposed: Bh/Bl[n][k] bf16, rowstride K.
// 3-term bf16 split product: Ah*Bh + Ah*Bl + Al*Bh  (~f32 accuracy).
__global__ __launch_bounds__(256) void gemm_mfma(const float* __restrict__ A,
                                                 const ushort* __restrict__ Bh,
                                                 const ushort* __restrict__ Bl,
                                                 const float* __restrict__ bias,
                                                 float* __restrict__ C,
                                                 int M, int K) {
    __shared__ __align__(16) ushort sAh[8192], sAl[8192], sBh[8192], sBl[8192];
    int tid = threadIdx.x;
    int m0 = blockIdx.x * 128, n0 = blockIdx.y * 128;
    int wid = tid >> 6, lane = tid & 63;
    int wm = wid & 1, wn = wid >> 1;
    int lr = lane & 15, grp = lane >> 4;
    f32x4 acc[4][4];
#pragma unroll
    for (int i = 0; i < 4; ++i)
#pragma unroll
        for (int j = 0; j < 4; ++j) acc[i][j] = (f32x4){0.f, 0.f, 0.f, 0.f};

    int mrow = tid >> 1, half = tid & 1;
    bool mvalid = (m0 + mrow) < M;
    const float* ap = A + (size_t)(m0 + mrow) * K + half * 32;
    const ushort* bph = Bh + (size_t)(n0 + mrow) * K + half * 32;
    const ushort* bpl = Bl + (size_t)(n0 + mrow) * K + half * 32;
    int swzA = (mrow & 7) << 3;

    for (int k0 = 0; k0 < K; k0 += 64) {
        if (k0) __syncthreads();
        // stage A: f32 -> hi(RTZ)/lo(RN) bf16
#pragma unroll
        for (int i = 0; i < 8; ++i) {
            float4 v;
            if (mvalid) v = *(const float4*)(ap + k0 + i * 4);
            else        v = make_float4(0.f, 0.f, 0.f, 0.f);
            int kk = half * 32 + i * 4;
            int off = mrow * 64 + (kk ^ swzA);
            float f[4] = {v.x, v.y, v.z, v.w};
            ushort hh[4], ll[4];
#pragma unroll
            for (int c = 0; c < 4; ++c) {
                union { float f; uint u; } uv; uv.f = f[c];
                ushort hi = (ushort)(uv.u >> 16);
                hh[c] = hi;
                ll[c] = f2bf_rn(f[c] - bf2f(hi));
            }
            uint2 ph = {(uint)hh[0] | ((uint)hh[1] << 16), (uint)hh[2] | ((uint)hh[3] << 16)};
            uint2 pl = {(uint)ll[0] | ((uint)ll[1] << 16), (uint)ll[2] | ((uint)ll[3] << 16)};
            *(uint2*)&sAh[off] = ph;
            *(uint2*)&sAl[off] = pl;
        }
        // stage B: straight bf16 copy
#pragma unroll
        for (int i = 0; i < 4; ++i) {
            int kk = half * 32 + i * 8;
            int off = mrow * 64 + (kk ^ swzA);
            *(uint4*)&sBh[off] = *(const uint4*)(bph + k0 + i * 8);
            *(uint4*)&sBl[off] = *(const uint4*)(bpl + k0 + i * 8);
        }
        __syncthreads();
#pragma unroll
        for (int ks = 0; ks < 2; ++ks) {
            bf16x8 vbh[4], vbl[4];
#pragma unroll
            for (int j = 0; j < 4; ++j) {
                int n = wn * 64 + j * 16 + lr;
                int off = n * 64 + ((ks * 32 + grp * 8) ^ ((n & 7) << 3));
                vbh[j] = *(const bf16x8*)&sBh[off];
                vbl[j] = *(const bf16x8*)&sBl[off];
            }
#pragma unroll
            for (int i = 0; i < 4; ++i) {
                int mm = wm * 64 + i * 16 + lr;
                int off = mm * 64 + ((ks * 32 + grp * 8) ^ ((mm & 7) << 3));
                bf16x8 vah = *(const bf16x8*)&sAh[off];
                bf16x8 valo = *(const bf16x8*)&sAl[off];
#pragma unroll
                for (int j = 0; j < 4; ++j) {
                    acc[i][j] = __builtin_amdgcn_mfma_f32_16x16x32_bf16(valo, vbh[j], acc[i][j], 0, 0, 0);
                    acc[i][j] = __builtin_amdgcn_mfma_f32_16x16x32_bf16(vah, vbl[j], acc[i][j], 0, 0, 0);
                    acc[i][j] = __builtin_amdgcn_mfma_f32_16x16x32_bf16(vah, vbh[j], acc[i][j], 0, 0, 0);
                }
            }
        }
    }
    // epilogue: C/D layout col=lane&15, row=(lane>>4)*4+reg [m89-verified]
#pragma unroll
    for (int j = 0; j < 4; ++j) {
        int c = n0 + wn * 64 + j * 16 + lr;
        float bj = bias ? bias[c] : 0.f;
#pragma unroll
        for (int i = 0; i < 4; ++i) {
            int mb = m0 + wm * 64 + i * 16 + grp * 4;
#pragma unroll
            for (int r = 0; r < 4; ++r)
                if (mb + r < M) C[(size_t)(mb + r) * 256 + c] = acc[i][j][r] + bj;
        }
    }
}

// ---------------- per-layer kernels ----------------

__global__ __launch_bounds__(256) void a_sd_kernel(const float* __restrict__ hp,
                                                   const float* __restrict__ att_s,
                                                   const float* __restrict__ att_d,
                                                   float* __restrict__ a_s,
                                                   float* __restrict__ a_d) {
    int idx = blockIdx.x * 256 + threadIdx.x;
    if (idx >= NN * 8) return;
    int n = idx >> 3, hh = idx & 7;
    const float* base = hp + (size_t)n * 256 + hh * 32;
    const float* as = att_s + hh * 32;
    const float* ad = att_d + hh * 32;
    float ss = 0.f, sd = 0.f;
#pragma unroll
    for (int c = 0; c < 32; ++c) {
        float vv = base[c];
        ss += vv * as[c];
        sd += vv * ad[c];
    }
    a_s[idx] = ss;
    a_d[idx] = sd;
}

__global__ __launch_bounds__(256) void e_edge_kernel(const float* __restrict__ edge_attr,
                                                     const float* __restrict__ mean_ea,
                                                     const int* __restrict__ sorted_eid,
                                                     const float* __restrict__ v,  // +l*256
                                                     float* __restrict__ e_edge) {
    __shared__ float vs[256];
    vs[threadIdx.x] = v[threadIdx.x];
    __syncthreads();
    int p = blockIdx.x * 256 + threadIdx.x;
    if (p >= ETOT) return;
    int eid = sorted_eid[p];
    const float* row = (eid < EE) ? (edge_attr + (size_t)eid * 32) : mean_ea;
    float acc[8] = {};
#pragma unroll
    for (int d = 0; d < 32; ++d) {
        float rv = row[d];
#pragma unroll
        for (int h = 0; h < 8; ++h) acc[h] += rv * vs[d * 8 + h];
    }
#pragma unroll
    for (int h = 0; h < 8; ++h) e_edge[(size_t)p * 8 + h] = acc[h];
}

// one wave per dst node: SINGLE-PASS online softmax + weighted gather-sum
__global__ __launch_bounds__(256) void aggregate_kernel(const float* __restrict__ hp,
                                                        const float* __restrict__ a_s,
                                                        const float* __restrict__ a_d,
                                                        const float* __restrict__ e_edge,
                                                        const int* __restrict__ sorted_src,
                                                        const int* __restrict__ row_ptr,
                                                        const float* __restrict__ bias,  // +l*256
                                                        float* __restrict__ hnew) {
    int n = (blockIdx.x * 256 + threadIdx.x) >> 6;
    if (n >= NN) return;
    int lane = threadIdx.x & 63;
    int h = lane >> 3;  // lane*4 channels == head (lane>>3), chan group (lane&7)
    int beg = row_ptr[n], end = row_ptr[n + 1];
    float ad = a_d[n * 8 + h];
    float m = -1e30f, s = 0.f;
    float a0 = 0.f, a1 = 0.f, a2 = 0.f, a3 = 0.f;
    for (int j = beg; j < end; ++j) {
        int src = sorted_src[j];
        float e = a_s[src * 8 + h] + ad + e_edge[(size_t)j * 8 + h];
        e = (e >= 0.f) ? e : NEG_SLOPE * e;
        float nm = fmaxf(m, e);
        float sc = __expf(m - nm);
        float w = __expf(e - nm);
        s = s * sc + w;
        const float4 hv = *(const float4*)&hp[(size_t)src * 256 + lane * 4];
        a0 = a0 * sc + w * hv.x;
        a1 = a1 * sc + w * hv.y;
        a2 = a2 * sc + w * hv.z;
        a3 = a3 * sc + w * hv.w;
        m = nm;
    }
    float inv = 1.0f / (s + 1e-16f);
    float4 b4 = *(const float4*)&bias[lane * 4];
    float4 o = {a0 * inv + b4.x, a1 * inv + b4.y, a2 * inv + b4.z, a3 * inv + b4.w};
    *(float4*)&hnew[(size_t)n * 256 + lane * 4] = o;
}

__global__ __launch_bounds__(256) void out_kernel(const float* __restrict__ h,
                                                  const float* __restrict__ w_out,
                                                  const float* __restrict__ b_out,
                                                  float* __restrict__ out) {
    int n = (blockIdx.x * 256 + threadIdx.x) >> 6;
    if (n >= NN) return;
    int lane = threadIdx.x & 63;
    const float4 hv = *(const float4*)&h[(size_t)n * 256 + lane * 4];
    const float4 wv = *(const float4*)&w_out[lane * 4];
    float s = hv.x * wv.x + hv.y * wv.y + hv.z * wv.z + hv.w * wv.w;
    for (int off = 1; off < 64; off <<= 1) s += __shfl_xor(s, off);
    if (lane == 0) out[n] = s + b_out[0];
}

// ---------------- launch ----------------

extern "C" void kernel_launch(void* const* d_in, const int* in_sizes, int n_in,
                              void* d_out, int out_size, void* d_ws, size_t ws_size,
                              hipStream_t stream) {
    const float* x         = (const float*)d_in[0];
    const int*   edge_idx  = (const int*)d_in[1];
    const float* edge_attr = (const float*)d_in[2];
    const float* w_in      = (const float*)d_in[3];
    const float* b_in      = (const float*)d_in[4];
    const float* W_l       = (const float*)d_in[5];
    const float* We_l      = (const float*)d_in[6];
    const float* att_src   = (const float*)d_in[7];
    const float* att_dst   = (const float*)d_in[8];
    const float* att_edge  = (const float*)d_in[9];
    const float* bias_l    = (const float*)d_in[10];
    const float* w_out     = (const float*)d_in[11];
    const float* b_out     = (const float*)d_in[12];
    float* out = (float*)d_out;

    char* ws = (char*)d_ws;
    size_t off = 0;
    auto alloc = [&](size_t bytes) -> void* {
        void* p = ws + off;
        off = (off + bytes + 255) & ~(size_t)255;
        return p;
    };
    float*  h          = (float*)alloc((size_t)NN * EMB * 4);
    float*  hp         = (float*)alloc((size_t)NN * EMB * 4);
    float*  a_s        = (float*)alloc((size_t)NN * HH * 4);
    float*  a_d        = (float*)alloc((size_t)NN * HH * 4);
    float*  e_edge     = (float*)alloc((size_t)ETOT * HH * 4);
    int*    sorted_src = (int*)alloc((size_t)ETOT * 4);
    int*    sorted_eid = (int*)alloc((size_t)ETOT * 4);
    int*    row_ptr    = (int*)alloc((size_t)(NN + 1) * 4);
    int*    fill       = (int*)alloc((size_t)NN * 4);
    int*    cnt        = (int*)alloc((size_t)NN * 4);
    float*  mean_accum = (float*)alloc(32 * 4);
    float*  mean_ea    = (float*)alloc(32 * 4);
    float*  v          = (float*)alloc(1024 * 4);
    ushort* bsp_hi     = (ushort*)alloc((size_t)294912 * 2);
    ushort* bsp_lo     = (ushort*)alloc((size_t)294912 * 2);

    // graph build + weight prep (layer-invariant)
    zero_int_kernel<<<(NN + 255) / 256, 256, 0, stream>>>(cnt, NN);
    zero_int_kernel<<<1, 256, 0, stream>>>((int*)mean_accum, 32);
    mean_kernel<<<512, 256, 0, stream>>>(edge_attr, mean_accum);
    precompute_kernel<<<1, 1024, 0, stream>>>(mean_accum, We_l, att_edge, mean_ea, v);
    split_weights<<<(294912 + 255) / 256, 256, 0, stream>>>(w_in, W_l, bsp_hi, bsp_lo);
    hist_kernel<<<(ETOT + 255) / 256, 256, 0, stream>>>(edge_idx, cnt);
    scan_kernel<<<1, 1024, 0, stream>>>(cnt, row_ptr, fill);
    scatter_kernel<<<(ETOT + 255) / 256, 256, 0, stream>>>(edge_idx, fill, sorted_src, sorted_eid);

    dim3 ggrid((NN + 127) / 128, 2);
    // input projection: h = x @ w_in + b_in
    gemm_mfma<<<ggrid, 256, 0, stream>>>(x, bsp_hi, bsp_lo, b_in, h, NN, IN_DIM);

    for (int l = 0; l < LL; ++l) {
        const ushort* wh = bsp_hi + 32768 + (size_t)l * 65536;
        const ushort* wl = bsp_lo + 32768 + (size_t)l * 65536;
        gemm_mfma<<<ggrid, 256, 0, stream>>>(h, wh, wl, nullptr, hp, NN, EMB);
        a_sd_kernel<<<(NN * 8 + 255) / 256, 256, 0, stream>>>(
            hp, att_src + l * 256, att_dst + l * 256, a_s, a_d);
        e_edge_kernel<<<(ETOT + 255) / 256, 256, 0, stream>>>(
            edge_attr, mean_ea, sorted_eid, v + l * 256, e_edge);
        aggregate_kernel<<<NN / 4, 256, 0, stream>>>(
            hp, a_s, a_d, e_edge, sorted_src, row_ptr, bias_l + l * 256, h);
    }

    out_kernel<<<NN / 4, 256, 0, stream>>>(h, w_out, b_out, out);
}

// Round 3
// 1003.546 us; speedup vs baseline: 1.4864x; 1.2855x over previous
//
#include <hip/hip_runtime.h>

#define NN 50000
#define MPAD 50048
#define EE 800000
#define ETOT (EE + NN)
#define IN_DIM 128
#define EDGE_DIM 32
#define EMB 256
#define HH 8
#define LL 4
#define NEG_SLOPE 0.2f

typedef __attribute__((ext_vector_type(8))) short bf16x8;
typedef __attribute__((ext_vector_type(4))) float f32x4;

__device__ inline ushort f2bf_rn(float x) {
    union { float f; uint u; } v; v.f = x;
    uint r = v.u + 0x7FFFu + ((v.u >> 16) & 1u);
    return (ushort)(r >> 16);
}
__device__ inline float bf2f(ushort b) {
    union { uint u; float f; } v; v.u = ((uint)b) << 16;
    return v.f;
}

__device__ __forceinline__ void g2l16(const void* g, void* l) {
    __builtin_amdgcn_global_load_lds((const __attribute__((address_space(1))) void*)g,
                                     (__attribute__((address_space(3))) void*)l, 16, 0, 0);
}

// ---------------- small utility kernels ----------------

__global__ void zero_int_kernel(int* p, int n) {
    int i = blockIdx.x * 256 + threadIdx.x;
    if (i < n) p[i] = 0;
}

__global__ __launch_bounds__(256) void mean_kernel(const float* __restrict__ ea,
                                                   float* __restrict__ accum) {
    __shared__ float part[256];
    int d = threadIdx.x & 31;
    int g = threadIdx.x >> 5;
    float s = 0.f;
    for (int e = blockIdx.x * 8 + g; e < EE; e += gridDim.x * 8)
        s += ea[(size_t)e * 32 + d];
    part[threadIdx.x] = s;
    __syncthreads();
    if (g == 0) {
        float t = part[d];
        for (int k = 1; k < 8; ++k) t += part[k * 32 + d];
        atomicAdd(&accum[d], t);
    }
}

// finalize mean_ea; v[l][d][h] = sum_c We[l][d][h*32+c]*att_edge[l][h][c]
__global__ void precompute_kernel(const float* __restrict__ accum,
                                  const float* __restrict__ We,
                                  const float* __restrict__ att_e,
                                  float* __restrict__ mean_ea,
                                  float* __restrict__ v) {
    int t = threadIdx.x;  // 1024 threads
    if (t < 32) mean_ea[t] = accum[t] * (1.0f / EE);
    int l = t >> 8, rem = t & 255, d = rem >> 3, hh = rem & 7;
    float s = 0.f;
#pragma unroll
    for (int c = 0; c < 32; ++c)
        s += We[((size_t)(l * 32 + d)) * 256 + hh * 32 + c] * att_e[l * 256 + hh * 32 + c];
    v[t] = s;  // v[l*256 + d*8 + h]
}

__global__ void hist_kernel(const int* __restrict__ ei, int* __restrict__ cnt) {
    int i = blockIdx.x * 256 + threadIdx.x;
    if (i >= ETOT) return;
    int dst = (i < EE) ? ei[EE + i] : (i - EE);
    atomicAdd(&cnt[dst], 1);
}

// 3-phase scan over cnt[NN] -> row_ptr/fill (1024 elems per block)
__global__ __launch_bounds__(256) void scan_phase1(const int* __restrict__ cnt,
                                                   int* __restrict__ bsum) {
    int b = blockIdx.x, t = threadIdx.x;
    int i0 = b * 1024 + t * 4;
    int s = 0;
#pragma unroll
    for (int r = 0; r < 4; ++r) s += (i0 + r < NN) ? cnt[i0 + r] : 0;
    for (int off = 1; off < 64; off <<= 1) s += __shfl_xor(s, off);
    __shared__ int wtot[4];
    if ((t & 63) == 0) wtot[t >> 6] = s;
    __syncthreads();
    if (t == 0) bsum[b] = wtot[0] + wtot[1] + wtot[2] + wtot[3];
}

__global__ void scan_phase2(int* __restrict__ bsum, int* __restrict__ row_ptr, int nb) {
    int lane = threadIdx.x;  // 64 threads
    int vv = (lane < nb) ? bsum[lane] : 0;
    int incl = vv;
    for (int off = 1; off < 64; off <<= 1) {
        int u = __shfl_up(incl, off);
        if (lane >= off) incl += u;
    }
    if (lane < nb) bsum[lane] = incl - vv;
    if (lane == 0) row_ptr[NN] = ETOT;
}

__global__ __launch_bounds__(256) void scan_phase3(const int* __restrict__ cnt,
                                                   const int* __restrict__ bsum,
                                                   int* __restrict__ row_ptr,
                                                   int* __restrict__ fill) {
    int b = blockIdx.x, t = threadIdx.x;
    int i0 = b * 1024 + t * 4;
    int v[4];
    int s = 0;
#pragma unroll
    for (int r = 0; r < 4; ++r) { v[r] = (i0 + r < NN) ? cnt[i0 + r] : 0; s += v[r]; }
    int lane = t & 63, wv = t >> 6;
    int incl = s;
    for (int off = 1; off < 64; off <<= 1) {
        int u = __shfl_up(incl, off);
        if (lane >= off) incl += u;
    }
    __shared__ int wtot[4];
    if (lane == 63) wtot[wv] = incl;
    __syncthreads();
    int wpref = 0;
    for (int k = 0; k < wv; ++k) wpref += wtot[k];
    int start = bsum[b] + wpref + incl - s;
#pragma unroll
    for (int r = 0; r < 4; ++r) {
        int i = i0 + r;
        if (i < NN) { row_ptr[i] = start; fill[i] = start; }
        start += v[r];
    }
}

__global__ void scatter_kernel(const int* __restrict__ ei, int* __restrict__ fill,
                               int* __restrict__ sorted_src, int* __restrict__ eid2pos) {
    int i = blockIdx.x * 256 + threadIdx.x;
    if (i >= ETOT) return;
    int dst, src;
    if (i < EE) { src = ei[i]; dst = ei[EE + i]; }
    else        { src = i - EE; dst = i - EE; }
    int pos = atomicAdd(&fill[dst], 1);
    sorted_src[pos] = src;
    eid2pos[i] = pos;
}

// split weights into transposed [n][k] bf16 hi/lo panels
__global__ __launch_bounds__(256) void split_weights(const float* __restrict__ w_in,
                                                     const float* __restrict__ W_l,
                                                     ushort* __restrict__ bh,
                                                     ushort* __restrict__ bl) {
    int t = blockIdx.x * 256 + threadIdx.x;
    if (t >= 32768 + 4 * 65536) return;
    float val;
    size_t dst;
    if (t < 32768) {
        int n = t >> 7, k = t & 127;
        val = w_in[(size_t)k * 256 + n];
        dst = (size_t)n * 128 + k;
    } else {
        int u = t - 32768;
        int l = u >> 16, r = u & 65535;
        int n = r >> 8, k = r & 255;
        val = W_l[(size_t)l * 65536 + (size_t)k * 256 + n];
        dst = 32768 + (size_t)l * 65536 + (size_t)n * 256 + k;
    }
    ushort hi = f2bf_rn(val);
    bh[dst] = hi;
    bl[dst] = f2bf_rn(val - bf2f(hi));
}

// pre-split x into bf16 hi(trunc)/lo(RN), zero-padded to MPAD rows
__global__ void split_x(const float* __restrict__ x, ushort* __restrict__ xh,
                        ushort* __restrict__ xl) {
    int i = blockIdx.x * 256 + threadIdx.x;
    if (i >= MPAD * 128) return;
    int n = i >> 7;
    float val = (n < NN) ? x[i] : 0.f;
    union { float f; uint u; } uv; uv.f = val;
    ushort hi = (ushort)(uv.u >> 16);
    xh[i] = hi;
    xl[i] = f2bf_rn(val - bf2f(hi));
}

// all-layer edge logits: stream edge_attr coalesced, scatter fp16 to sorted pos
__global__ __launch_bounds__(256) void edge_logits(const float* __restrict__ edge_attr,
                                                   const float* __restrict__ mean_ea,
                                                   const int* __restrict__ eid2pos,
                                                   const float* __restrict__ v,
                                                   _Float16* __restrict__ e_all) {
    __shared__ float vs[1024];
    for (int t = threadIdx.x; t < 1024; t += 256) vs[t] = v[t];
    __syncthreads();
    int i = blockIdx.x * 256 + threadIdx.x;
    if (i >= ETOT) return;
    int pos = eid2pos[i];
    const float* row = (i < EE) ? (edge_attr + (size_t)i * 32) : mean_ea;
    float acc[4][8] = {};
#pragma unroll 4
    for (int d = 0; d < 32; ++d) {
        float rv = row[d];
#pragma unroll
        for (int l = 0; l < 4; ++l)
#pragma unroll
            for (int h = 0; h < 8; ++h) acc[l][h] += rv * vs[l * 256 + d * 8 + h];
    }
#pragma unroll
    for (int l = 0; l < 4; ++l) {
        union { uint4 u; _Float16 h[8]; } p;
#pragma unroll
        for (int h = 0; h < 8; ++h) p.h[h] = (_Float16)acc[l][h];
        *(uint4*)&e_all[(size_t)l * ETOT * 8 + (size_t)pos * 8] = p.u;
    }
}

// ---------------- MFMA GEMM ----------------
// A pre-split bf16 hi/lo [row][K]; B pre-split transposed [n][K] hi/lo.
// 3-term: Ah*Bh + Ah*Bl + Al*Bh. Staging via global_load_lds w/ pre-swizzled source.
// MODE 0: out = h pair (bf16 hi/lo) + bias. MODE 1: out = hp fp16, no bias.
template <int MODE>
__global__ __launch_bounds__(256) void gemm_mfma(const ushort* __restrict__ Ah,
                                                 const ushort* __restrict__ Al,
                                                 const ushort* __restrict__ Bh,
                                                 const ushort* __restrict__ Bl,
                                                 const float* __restrict__ bias,
                                                 _Float16* __restrict__ hp_out,
                                                 ushort* __restrict__ hh_out,
                                                 ushort* __restrict__ hl_out,
                                                 int M, int K) {
    __shared__ __align__(16) ushort sAh[8192], sAl[8192], sBh[8192], sBl[8192];
    int tid = threadIdx.x;
    int m0 = blockIdx.x * 128, n0 = blockIdx.y * 128;
    int wid = tid >> 6, lane = tid & 63;
    int wm = wid & 1, wn = wid >> 1;
    int lr = lane & 15, grp = lane >> 4;
    f32x4 acc[4][4];
#pragma unroll
    for (int i = 0; i < 4; ++i)
#pragma unroll
        for (int j = 0; j < 4; ++j) acc[i][j] = (f32x4){0.f, 0.f, 0.f, 0.f};

    for (int k0 = 0; k0 < K; k0 += 64) {
        if (k0) __syncthreads();
        // stage 4 operand images; LDS linear, swizzle folded into global source addr
#pragma unroll
        for (int i = 0; i < 4; ++i) {
            int ldso = wid * 2048 + i * 512;           // ushort units, wave-uniform
            int o = ldso + lane * 8;
            int m = o >> 6;                             // local row (64 ushorts/row)
            int kl = ((((o >> 3) & 7) ^ (m & 7)) << 3) + k0;
            size_t ga = (size_t)(m0 + m) * K + kl;
            size_t gb = (size_t)(n0 + m) * K + kl;
            g2l16(Ah + ga, sAh + ldso);
            g2l16(Al + ga, sAl + ldso);
            g2l16(Bh + gb, sBh + ldso);
            g2l16(Bl + gb, sBl + ldso);
        }
        __syncthreads();
#pragma unroll
        for (int ks = 0; ks < 2; ++ks) {
            bf16x8 vbh[4], vbl[4];
#pragma unroll
            for (int j = 0; j < 4; ++j) {
                int n = wn * 64 + j * 16 + lr;
                int off = n * 64 + ((ks * 32 + grp * 8) ^ ((n & 7) << 3));
                vbh[j] = *(const bf16x8*)&sBh[off];
                vbl[j] = *(const bf16x8*)&sBl[off];
            }
#pragma unroll
            for (int i = 0; i < 4; ++i) {
                int mm = wm * 64 + i * 16 + lr;
                int off = mm * 64 + ((ks * 32 + grp * 8) ^ ((mm & 7) << 3));
                bf16x8 vah = *(const bf16x8*)&sAh[off];
                bf16x8 valo = *(const bf16x8*)&sAl[off];
#pragma unroll
                for (int j = 0; j < 4; ++j) {
                    acc[i][j] = __builtin_amdgcn_mfma_f32_16x16x32_bf16(valo, vbh[j], acc[i][j], 0, 0, 0);
                    acc[i][j] = __builtin_amdgcn_mfma_f32_16x16x32_bf16(vah, vbl[j], acc[i][j], 0, 0, 0);
                    acc[i][j] = __builtin_amdgcn_mfma_f32_16x16x32_bf16(vah, vbh[j], acc[i][j], 0, 0, 0);
                }
            }
        }
    }
    // epilogue: C/D layout col=lane&15, row=(lane>>4)*4+reg [m89-verified]
#pragma unroll
    for (int j = 0; j < 4; ++j) {
        int c = n0 + wn * 64 + j * 16 + lr;
        float bj = (MODE == 0) ? bias[c] : 0.f;
#pragma unroll
        for (int i = 0; i < 4; ++i) {
            int mb = m0 + wm * 64 + i * 16 + grp * 4;
#pragma unroll
            for (int r = 0; r < 4; ++r) {
                int row = mb + r;
                if (row < M) {
                    float val = acc[i][j][r] + bj;
                    if (MODE == 0) {
                        union { float f; uint u; } uv; uv.f = val;
                        ushort hi = (ushort)(uv.u >> 16);
                        hh_out[(size_t)row * 256 + c] = hi;
                        hl_out[(size_t)row * 256 + c] = f2bf_rn(val - bf2f(hi));
                    } else {
                        hp_out[(size_t)row * 256 + c] = (_Float16)val;
                    }
                }
            }
        }
    }
}

// ---------------- per-layer kernels ----------------

__global__ __launch_bounds__(256) void a_sd_kernel(const _Float16* __restrict__ hp,
                                                   const float* __restrict__ att_s,
                                                   const float* __restrict__ att_d,
                                                   float* __restrict__ a_s,
                                                   float* __restrict__ a_d) {
    int idx = blockIdx.x * 256 + threadIdx.x;
    if (idx >= NN * 8) return;
    int n = idx >> 3, hh = idx & 7;
    const _Float16* base = hp + (size_t)n * 256 + hh * 32;
    const float* as = att_s + hh * 32;
    const float* ad = att_d + hh * 32;
    float ss = 0.f, sd = 0.f;
#pragma unroll
    for (int c = 0; c < 32; ++c) {
        float vv = (float)base[c];
        ss += vv * as[c];
        sd += vv * ad[c];
    }
    a_s[idx] = ss;
    a_d[idx] = sd;
}

// one wave per dst node: single-pass online softmax + fp16 gather-sum
__global__ __launch_bounds__(256) void aggregate_kernel(const _Float16* __restrict__ hp,
                                                        const float* __restrict__ a_s,
                                                        const float* __restrict__ a_d,
                                                        const _Float16* __restrict__ e_l,
                                                        const int* __restrict__ sorted_src,
                                                        const int* __restrict__ row_ptr,
                                                        const float* __restrict__ bias,
                                                        ushort* __restrict__ h_hi,
                                                        ushort* __restrict__ h_lo) {
    int n = (blockIdx.x * 256 + threadIdx.x) >> 6;
    if (n >= NN) return;
    int lane = threadIdx.x & 63;
    int h = lane >> 3;
    int beg = row_ptr[n], end = row_ptr[n + 1];
    float ad = a_d[n * 8 + h];
    float m = -1e30f, s = 0.f;
    float a0 = 0.f, a1 = 0.f, a2 = 0.f, a3 = 0.f;
    for (int j = beg; j < end; ++j) {
        int src = sorted_src[j];
        float e = a_s[src * 8 + h] + ad + (float)e_l[(size_t)j * 8 + h];
        e = (e >= 0.f) ? e : NEG_SLOPE * e;
        float nm = fmaxf(m, e);
        float sc = __expf(m - nm);
        float w = __expf(e - nm);
        s = s * sc + w;
        union { uint2 u; _Float16 q[4]; } hv;
        hv.u = *(const uint2*)&hp[(size_t)src * 256 + lane * 4];
        a0 = a0 * sc + w * (float)hv.q[0];
        a1 = a1 * sc + w * (float)hv.q[1];
        a2 = a2 * sc + w * (float)hv.q[2];
        a3 = a3 * sc + w * (float)hv.q[3];
        m = nm;
    }
    float inv = 1.0f / (s + 1e-16f);
    float4 b4 = *(const float4*)&bias[lane * 4];
    float o[4] = {a0 * inv + b4.x, a1 * inv + b4.y, a2 * inv + b4.z, a3 * inv + b4.w};
    ushort4 vhi, vlo;
    ushort* ph = (ushort*)&vhi;
    ushort* pl = (ushort*)&vlo;
#pragma unroll
    for (int c = 0; c < 4; ++c) {
        union { float f; uint u; } uv; uv.f = o[c];
        ph[c] = (ushort)(uv.u >> 16);
        pl[c] = f2bf_rn(o[c] - bf2f(ph[c]));
    }
    *(ushort4*)&h_hi[(size_t)n * 256 + lane * 4] = vhi;
    *(ushort4*)&h_lo[(size_t)n * 256 + lane * 4] = vlo;
}

__global__ __launch_bounds__(256) void out_kernel(const ushort* __restrict__ h_hi,
                                                  const ushort* __restrict__ h_lo,
                                                  const float* __restrict__ w_out,
                                                  const float* __restrict__ b_out,
                                                  float* __restrict__ out) {
    int n = (blockIdx.x * 256 + threadIdx.x) >> 6;
    if (n >= NN) return;
    int lane = threadIdx.x & 63;
    union { uint2 u; ushort s[4]; } uh, ul;
    uh.u = *(const uint2*)&h_hi[(size_t)n * 256 + lane * 4];
    ul.u = *(const uint2*)&h_lo[(size_t)n * 256 + lane * 4];
    const float4 wv = *(const float4*)&w_out[lane * 4];
    float s = (bf2f(uh.s[0]) + bf2f(ul.s[0])) * wv.x +
              (bf2f(uh.s[1]) + bf2f(ul.s[1])) * wv.y +
              (bf2f(uh.s[2]) + bf2f(ul.s[2])) * wv.z +
              (bf2f(uh.s[3]) + bf2f(ul.s[3])) * wv.w;
    for (int off = 1; off < 64; off <<= 1) s += __shfl_xor(s, off);
    if (lane == 0) out[n] = s + b_out[0];
}

// ---------------- launch ----------------

extern "C" void kernel_launch(void* const* d_in, const int* in_sizes, int n_in,
                              void* d_out, int out_size, void* d_ws, size_t ws_size,
                              hipStream_t stream) {
    const float* x         = (const float*)d_in[0];
    const int*   edge_idx  = (const int*)d_in[1];
    const float* edge_attr = (const float*)d_in[2];
    const float* w_in      = (const float*)d_in[3];
    const float* b_in      = (const float*)d_in[4];
    const float* W_l       = (const float*)d_in[5];
    const float* We_l      = (const float*)d_in[6];
    const float* att_src   = (const float*)d_in[7];
    const float* att_dst   = (const float*)d_in[8];
    const float* att_edge  = (const float*)d_in[9];
    const float* bias_l    = (const float*)d_in[10];
    const float* w_out     = (const float*)d_in[11];
    const float* b_out     = (const float*)d_in[12];
    float* out = (float*)d_out;

    char* ws = (char*)d_ws;
    size_t off = 0;
    auto alloc = [&](size_t bytes) -> void* {
        void* p = ws + off;
        off = (off + bytes + 255) & ~(size_t)255;
        return p;
    };
    ushort*   h_hi       = (ushort*)alloc((size_t)MPAD * 256 * 2);
    ushort*   h_lo       = (ushort*)alloc((size_t)MPAD * 256 * 2);
    _Float16* hp16       = (_Float16*)alloc((size_t)MPAD * 256 * 2);
    float*    a_s        = (float*)alloc((size_t)NN * 8 * 4);
    float*    a_d        = (float*)alloc((size_t)NN * 8 * 4);
    int*      sorted_src = (int*)alloc((size_t)ETOT * 4);
    int*      eid2pos    = (int*)alloc((size_t)ETOT * 4);
    int*      row_ptr    = (int*)alloc((size_t)(NN + 1) * 4);
    int*      fill       = (int*)alloc((size_t)NN * 4);
    int*      cnt        = (int*)alloc((size_t)NN * 4);
    int*      bsum       = (int*)alloc(64 * 4);
    float*    mean_accum = (float*)alloc(32 * 4);
    float*    mean_ea    = (float*)alloc(32 * 4);
    float*    v          = (float*)alloc(1024 * 4);
    ushort*   bsp_hi     = (ushort*)alloc((size_t)294912 * 2);
    ushort*   bsp_lo     = (ushort*)alloc((size_t)294912 * 2);
    // union region: {xh, xl} then (after input GEMM) e_all overlays it
    char*     uni        = (char*)alloc((size_t)4 * ETOT * 8 * 2);  // 54.4 MB
    ushort*   xh         = (ushort*)uni;
    ushort*   xl         = (ushort*)(uni + (size_t)MPAD * 128 * 2);
    _Float16* e_all      = (_Float16*)uni;

    const int NB = (NN + 1023) / 1024;  // 49

    // weight prep + input projection (uses xh/xl before e_all overlays)
    zero_int_kernel<<<(NN + 255) / 256, 256, 0, stream>>>(cnt, NN);
    zero_int_kernel<<<1, 256, 0, stream>>>((int*)mean_accum, 32);
    mean_kernel<<<512, 256, 0, stream>>>(edge_attr, mean_accum);
    precompute_kernel<<<1, 1024, 0, stream>>>(mean_accum, We_l, att_edge, mean_ea, v);
    split_weights<<<(294912 + 255) / 256, 256, 0, stream>>>(w_in, W_l, bsp_hi, bsp_lo);
    split_x<<<(MPAD * 128 + 255) / 256, 256, 0, stream>>>(x, xh, xl);

    dim3 ggrid((NN + 127) / 128, 2);
    gemm_mfma<0><<<ggrid, 256, 0, stream>>>(xh, xl, bsp_hi, bsp_lo, b_in,
                                            nullptr, h_hi, h_lo, NN, IN_DIM);

    // graph build + all-layer edge logits (e_all overlays xh/xl — input GEMM done)
    hist_kernel<<<(ETOT + 255) / 256, 256, 0, stream>>>(edge_idx, cnt);
    scan_phase1<<<NB, 256, 0, stream>>>(cnt, bsum);
    scan_phase2<<<1, 64, 0, stream>>>(bsum, row_ptr, NB);
    scan_phase3<<<NB, 256, 0, stream>>>(cnt, bsum, row_ptr, fill);
    scatter_kernel<<<(ETOT + 255) / 256, 256, 0, stream>>>(edge_idx, fill, sorted_src, eid2pos);
    edge_logits<<<(ETOT + 255) / 256, 256, 0, stream>>>(edge_attr, mean_ea, eid2pos, v, e_all);

    for (int l = 0; l < LL; ++l) {
        const ushort* wh = bsp_hi + 32768 + (size_t)l * 65536;
        const ushort* wl = bsp_lo + 32768 + (size_t)l * 65536;
        gemm_mfma<1><<<ggrid, 256, 0, stream>>>(h_hi, h_lo, wh, wl, nullptr,
                                                hp16, nullptr, nullptr, NN, EMB);
        a_sd_kernel<<<(NN * 8 + 255) / 256, 256, 0, stream>>>(
            hp16, att_src + l * 256, att_dst + l * 256, a_s, a_d);
        aggregate_kernel<<<NN / 4, 256, 0, stream>>>(
            hp16, a_s, a_d, e_all + (size_t)l * ETOT * 8, sorted_src, row_ptr,
            bias_l + l * 256, h_hi, h_lo);
    }

    out_kernel<<<NN / 4, 256, 0, stream>>>(h_hi, h_lo, w_out, b_out, out);
}

// Round 5
// 762.411 us; speedup vs baseline: 1.9565x; 1.3163x over previous
//
#include <hip/hip_runtime.h>

#define NN 50000
#define MPAD 50048
#define EE 800000
#define ETOT (EE + NN)
#define IN_DIM 128
#define EDGE_DIM 32
#define EMB 256
#define HH 8
#define LL 4
#define NEG_SLOPE 0.2f

typedef __attribute__((ext_vector_type(8))) short bf16x8;
typedef __attribute__((ext_vector_type(4))) float f32x4;

__device__ inline ushort f2bf_rn(float x) {
    union { float f; uint u; } v; v.f = x;
    uint r = v.u + 0x7FFFu + ((v.u >> 16) & 1u);
    return (ushort)(r >> 16);
}
__device__ inline float bf2f(ushort b) {
    union { uint u; float f; } v; v.u = ((uint)b) << 16;
    return v.f;
}

__device__ __forceinline__ void g2l16(const void* g, void* l) {
    __builtin_amdgcn_global_load_lds((const __attribute__((address_space(1))) void*)g,
                                     (__attribute__((address_space(3))) void*)l, 16, 0, 0);
}

// ---------------- small utility kernels ----------------

__global__ void zero_int_kernel(int* p, int n) {
    int i = blockIdx.x * 256 + threadIdx.x;
    if (i < n) p[i] = 0;
}

__global__ __launch_bounds__(256) void mean_kernel(const float* __restrict__ ea,
                                                   float* __restrict__ accum) {
    __shared__ float part[256];
    int d = threadIdx.x & 31;
    int g = threadIdx.x >> 5;
    float s = 0.f;
    for (int e = blockIdx.x * 8 + g; e < EE; e += gridDim.x * 8)
        s += ea[(size_t)e * 32 + d];
    part[threadIdx.x] = s;
    __syncthreads();
    if (g == 0) {
        float t = part[d];
        for (int k = 1; k < 8; ++k) t += part[k * 32 + d];
        atomicAdd(&accum[d], t);
    }
}

// finalize mean_ea; v[l][d][h] = sum_c We[l][d][h*32+c]*att_edge[l][h][c]
__global__ void precompute_kernel(const float* __restrict__ accum,
                                  const float* __restrict__ We,
                                  const float* __restrict__ att_e,
                                  float* __restrict__ mean_ea,
                                  float* __restrict__ v) {
    int t = threadIdx.x;  // 1024 threads
    if (t < 32) mean_ea[t] = accum[t] * (1.0f / EE);
    int l = t >> 8, rem = t & 255, d = rem >> 3, hh = rem & 7;
    float s = 0.f;
#pragma unroll
    for (int c = 0; c < 32; ++c)
        s += We[((size_t)(l * 32 + d)) * 256 + hh * 32 + c] * att_e[l * 256 + hh * 32 + c];
    v[t] = s;  // v[l*256 + d*8 + h]
}

__global__ void hist_kernel(const int* __restrict__ ei, int* __restrict__ cnt) {
    int i = blockIdx.x * 256 + threadIdx.x;
    if (i >= ETOT) return;
    int dst = (i < EE) ? ei[EE + i] : (i - EE);
    atomicAdd(&cnt[dst], 1);
}

// 3-phase scan over cnt[NN] -> row_ptr/fill (1024 elems per block)
__global__ __launch_bounds__(256) void scan_phase1(const int* __restrict__ cnt,
                                                   int* __restrict__ bsum) {
    int b = blockIdx.x, t = threadIdx.x;
    int i0 = b * 1024 + t * 4;
    int s = 0;
#pragma unroll
    for (int r = 0; r < 4; ++r) s += (i0 + r < NN) ? cnt[i0 + r] : 0;
    for (int off = 1; off < 64; off <<= 1) s += __shfl_xor(s, off);
    __shared__ int wtot[4];
    if ((t & 63) == 0) wtot[t >> 6] = s;
    __syncthreads();
    if (t == 0) bsum[b] = wtot[0] + wtot[1] + wtot[2] + wtot[3];
}

__global__ void scan_phase2(int* __restrict__ bsum, int* __restrict__ row_ptr, int nb) {
    int lane = threadIdx.x;  // 64 threads
    int vv = (lane < nb) ? bsum[lane] : 0;
    int incl = vv;
    for (int off = 1; off < 64; off <<= 1) {
        int u = __shfl_up(incl, off);
        if (lane >= off) incl += u;
    }
    if (lane < nb) bsum[lane] = incl - vv;
    if (lane == 0) row_ptr[NN] = ETOT;
}

__global__ __launch_bounds__(256) void scan_phase3(const int* __restrict__ cnt,
                                                   const int* __restrict__ bsum,
                                                   int* __restrict__ row_ptr,
                                                   int* __restrict__ fill) {
    int b = blockIdx.x, t = threadIdx.x;
    int i0 = b * 1024 + t * 4;
    int v[4];
    int s = 0;
#pragma unroll
    for (int r = 0; r < 4; ++r) { v[r] = (i0 + r < NN) ? cnt[i0 + r] : 0; s += v[r]; }
    int lane = t & 63, wv = t >> 6;
    int incl = s;
    for (int off = 1; off < 64; off <<= 1) {
        int u = __shfl_up(incl, off);
        if (lane >= off) incl += u;
    }
    __shared__ int wtot[4];
    if (lane == 63) wtot[wv] = incl;
    __syncthreads();
    int wpref = 0;
    for (int k = 0; k < wv; ++k) wpref += wtot[k];
    int start = bsum[b] + wpref + incl - s;
#pragma unroll
    for (int r = 0; r < 4; ++r) {
        int i = i0 + r;
        if (i < NN) { row_ptr[i] = start; fill[i] = start; }
        start += v[r];
    }
}

__global__ void scatter_kernel(const int* __restrict__ ei, int* __restrict__ fill,
                               int* __restrict__ sorted_src, int* __restrict__ sorted_eid) {
    int i = blockIdx.x * 256 + threadIdx.x;
    if (i >= ETOT) return;
    int dst, src;
    if (i < EE) { src = ei[i]; dst = ei[EE + i]; }
    else        { src = i - EE; dst = i - EE; }
    int pos = atomicAdd(&fill[dst], 1);
    sorted_src[pos] = src;
    sorted_eid[pos] = i;
}

// split weights into transposed [n][k] bf16 hi/lo panels
__global__ __launch_bounds__(256) void split_weights(const float* __restrict__ w_in,
                                                     const float* __restrict__ W_l,
                                                     ushort* __restrict__ bh,
                                                     ushort* __restrict__ bl) {
    int t = blockIdx.x * 256 + threadIdx.x;
    if (t >= 32768 + 4 * 65536) return;
    float val;
    size_t dst;
    if (t < 32768) {
        int n = t >> 7, k = t & 127;
        val = w_in[(size_t)k * 256 + n];
        dst = (size_t)n * 128 + k;
    } else {
        int u = t - 32768;
        int l = u >> 16, r = u & 65535;
        int n = r >> 8, k = r & 255;
        val = W_l[(size_t)l * 65536 + (size_t)k * 256 + n];
        dst = 32768 + (size_t)l * 65536 + (size_t)n * 256 + k;
    }
    ushort hi = f2bf_rn(val);
    bh[dst] = hi;
    bl[dst] = f2bf_rn(val - bf2f(hi));
}

// pre-split x into bf16 hi(trunc)/lo(RN), zero-padded to MPAD rows
__global__ void split_x(const float* __restrict__ x, ushort* __restrict__ xh,
                        ushort* __restrict__ xl) {
    int i = blockIdx.x * 256 + threadIdx.x;
    if (i >= MPAD * 128) return;
    int n = i >> 7;
    float val = (n < NN) ? x[i] : 0.f;
    union { float f; uint u; } uv; uv.f = val;
    ushort hi = (ushort)(uv.u >> 16);
    xh[i] = hi;
    xl[i] = f2bf_rn(val - bf2f(hi));
}

// all-layer edge logits in SORTED-POS order: gather edge_attr row (one full
// 128B line), write all 4 layer planes coalesced.
__global__ __launch_bounds__(256) void edge_logits(const float* __restrict__ edge_attr,
                                                   const float* __restrict__ mean_ea,
                                                   const int* __restrict__ sorted_eid,
                                                   const float* __restrict__ v,
                                                   _Float16* __restrict__ e_all) {
    __shared__ float vs[1024];
    for (int t = threadIdx.x; t < 1024; t += 256) vs[t] = v[t];
    __syncthreads();
    int p = blockIdx.x * 256 + threadIdx.x;
    if (p >= ETOT) return;
    int eid = sorted_eid[p];
    const float4* row = (const float4*)((eid < EE) ? (edge_attr + (size_t)eid * 32) : mean_ea);
    float r[32];
#pragma unroll
    for (int q = 0; q < 8; ++q) {
        float4 f = row[q];
        r[q * 4] = f.x; r[q * 4 + 1] = f.y; r[q * 4 + 2] = f.z; r[q * 4 + 3] = f.w;
    }
    float acc[4][8] = {};
#pragma unroll 4
    for (int d = 0; d < 32; ++d) {
        float rv = r[d];
#pragma unroll
        for (int l = 0; l < 4; ++l)
#pragma unroll
            for (int h = 0; h < 8; ++h) acc[l][h] += rv * vs[l * 256 + d * 8 + h];
    }
#pragma unroll
    for (int l = 0; l < 4; ++l) {
        union { uint4 u; _Float16 h[8]; } pk;
#pragma unroll
        for (int h = 0; h < 8; ++h) pk.h[h] = (_Float16)acc[l][h];
        *(uint4*)&e_all[(size_t)l * ETOT * 8 + (size_t)p * 8] = pk.u;
    }
}

// ---------------- MFMA GEMM ----------------
// A pre-split bf16 hi/lo [row][K]; B pre-split transposed [n][K] hi/lo.
// 3-term: Ah*Bh + Ah*Bl + Al*Bh. Staging via global_load_lds w/ pre-swizzled source.
// MODE 0: out = h pair (bf16 hi/lo) + bias. MODE 1: out = hp fp16, no bias.
template <int MODE>
__global__ __launch_bounds__(256) void gemm_mfma(const ushort* __restrict__ Ah,
                                                 const ushort* __restrict__ Al,
                                                 const ushort* __restrict__ Bh,
                                                 const ushort* __restrict__ Bl,
                                                 const float* __restrict__ bias,
                                                 _Float16* __restrict__ hp_out,
                                                 ushort* __restrict__ hh_out,
                                                 ushort* __restrict__ hl_out,
                                                 int M, int K) {
    __shared__ __align__(16) ushort sAh[8192], sAl[8192], sBh[8192], sBl[8192];
    int tid = threadIdx.x;
    int m0 = blockIdx.x * 128, n0 = blockIdx.y * 128;
    int wid = tid >> 6, lane = tid & 63;
    int wm = wid & 1, wn = wid >> 1;
    int lr = lane & 15, grp = lane >> 4;
    f32x4 acc[4][4];
#pragma unroll
    for (int i = 0; i < 4; ++i)
#pragma unroll
        for (int j = 0; j < 4; ++j) acc[i][j] = (f32x4){0.f, 0.f, 0.f, 0.f};

    for (int k0 = 0; k0 < K; k0 += 64) {
        if (k0) __syncthreads();
#pragma unroll
        for (int i = 0; i < 4; ++i) {
            int ldso = wid * 2048 + i * 512;           // ushort units, wave-uniform
            int o = ldso + lane * 8;
            int m = o >> 6;                             // local row (64 ushorts/row)
            int kl = ((((o >> 3) & 7) ^ (m & 7)) << 3) + k0;
            size_t ga = (size_t)(m0 + m) * K + kl;
            size_t gb = (size_t)(n0 + m) * K + kl;
            g2l16(Ah + ga, sAh + ldso);
            g2l16(Al + ga, sAl + ldso);
            g2l16(Bh + gb, sBh + ldso);
            g2l16(Bl + gb, sBl + ldso);
        }
        __syncthreads();
#pragma unroll
        for (int ks = 0; ks < 2; ++ks) {
            bf16x8 vbh[4], vbl[4];
#pragma unroll
            for (int j = 0; j < 4; ++j) {
                int n = wn * 64 + j * 16 + lr;
                int off = n * 64 + ((ks * 32 + grp * 8) ^ ((n & 7) << 3));
                vbh[j] = *(const bf16x8*)&sBh[off];
                vbl[j] = *(const bf16x8*)&sBl[off];
            }
#pragma unroll
            for (int i = 0; i < 4; ++i) {
                int mm = wm * 64 + i * 16 + lr;
                int off = mm * 64 + ((ks * 32 + grp * 8) ^ ((mm & 7) << 3));
                bf16x8 vah = *(const bf16x8*)&sAh[off];
                bf16x8 valo = *(const bf16x8*)&sAl[off];
#pragma unroll
                for (int j = 0; j < 4; ++j) {
                    acc[i][j] = __builtin_amdgcn_mfma_f32_16x16x32_bf16(valo, vbh[j], acc[i][j], 0, 0, 0);
                    acc[i][j] = __builtin_amdgcn_mfma_f32_16x16x32_bf16(vah, vbl[j], acc[i][j], 0, 0, 0);
                    acc[i][j] = __builtin_amdgcn_mfma_f32_16x16x32_bf16(vah, vbh[j], acc[i][j], 0, 0, 0);
                }
            }
        }
    }
    // epilogue: C/D layout col=lane&15, row=(lane>>4)*4+reg [m89-verified]
#pragma unroll
    for (int j = 0; j < 4; ++j) {
        int c = n0 + wn * 64 + j * 16 + lr;
        float bj = (MODE == 0) ? bias[c] : 0.f;
#pragma unroll
        for (int i = 0; i < 4; ++i) {
            int mb = m0 + wm * 64 + i * 16 + grp * 4;
#pragma unroll
            for (int r = 0; r < 4; ++r) {
                int row = mb + r;
                if (row < M) {
                    float val = acc[i][j][r] + bj;
                    if (MODE == 0) {
                        union { float f; uint u; } uv; uv.f = val;
                        ushort hi = (ushort)(uv.u >> 16);
                        hh_out[(size_t)row * 256 + c] = hi;
                        hl_out[(size_t)row * 256 + c] = f2bf_rn(val - bf2f(hi));
                    } else {
                        hp_out[(size_t)row * 256 + c] = (_Float16)val;
                    }
                }
            }
        }
    }
}

// ---------------- per-layer kernels ----------------

__global__ __launch_bounds__(256) void a_sd_kernel(const _Float16* __restrict__ hp,
                                                   const float* __restrict__ att_s,
                                                   const float* __restrict__ att_d,
                                                   float* __restrict__ a_s,
                                                   float* __restrict__ a_d) {
    int idx = blockIdx.x * 256 + threadIdx.x;
    if (idx >= NN * 8) return;
    int n = idx >> 3, hh = idx & 7;
    const uint4* base = (const uint4*)(hp + (size_t)n * 256 + hh * 32);
    const float4* as4 = (const float4*)(att_s + hh * 32);
    const float4* ad4 = (const float4*)(att_d + hh * 32);
    float ss = 0.f, sd = 0.f;
#pragma unroll
    for (int q = 0; q < 4; ++q) {
        union { uint4 u; _Float16 f[8]; } hv;
        hv.u = base[q];
        float4 s0 = as4[q * 2], s1 = as4[q * 2 + 1];
        float4 d0 = ad4[q * 2], d1 = ad4[q * 2 + 1];
        float f0 = (float)hv.f[0], f1 = (float)hv.f[1], f2 = (float)hv.f[2], f3 = (float)hv.f[3];
        float f4 = (float)hv.f[4], f5 = (float)hv.f[5], f6 = (float)hv.f[6], f7 = (float)hv.f[7];
        ss += f0 * s0.x + f1 * s0.y + f2 * s0.z + f3 * s0.w + f4 * s1.x + f5 * s1.y + f6 * s1.z + f7 * s1.w;
        sd += f0 * d0.x + f1 * d0.y + f2 * d0.z + f3 * d0.w + f4 * d1.x + f5 * d1.y + f6 * d1.z + f7 * d1.w;
    }
    a_s[idx] = ss;
    a_d[idx] = sd;
}

// one wave per dst node: single-pass online softmax, 4-way unrolled gathers
__global__ __launch_bounds__(256) void aggregate_kernel(const _Float16* __restrict__ hp,
                                                        const float* __restrict__ a_s,
                                                        const float* __restrict__ a_d,
                                                        const _Float16* __restrict__ e_l,
                                                        const int* __restrict__ sorted_src,
                                                        const int* __restrict__ row_ptr,
                                                        const float* __restrict__ bias,
                                                        ushort* __restrict__ h_hi,
                                                        ushort* __restrict__ h_lo) {
    int n = (blockIdx.x * 256 + threadIdx.x) >> 6;
    if (n >= NN) return;
    int lane = threadIdx.x & 63;
    int h = lane >> 3;
    int beg = row_ptr[n], end = row_ptr[n + 1];
    float ad = a_d[n * 8 + h];
    float m = -1e30f, s = 0.f;
    float a0 = 0.f, a1 = 0.f, a2 = 0.f, a3 = 0.f;
    int j = beg;
    for (; j + 3 < end; j += 4) {
        int s0 = sorted_src[j], s1 = sorted_src[j + 1];
        int s2 = sorted_src[j + 2], s3 = sorted_src[j + 3];
        float e0 = a_s[s0 * 8 + h] + ad + (float)e_l[(size_t)j * 8 + h];
        float e1 = a_s[s1 * 8 + h] + ad + (float)e_l[(size_t)(j + 1) * 8 + h];
        float e2 = a_s[s2 * 8 + h] + ad + (float)e_l[(size_t)(j + 2) * 8 + h];
        float e3 = a_s[s3 * 8 + h] + ad + (float)e_l[(size_t)(j + 3) * 8 + h];
        union { uint2 u; _Float16 q[4]; } v0, v1, v2, v3;
        v0.u = *(const uint2*)&hp[(size_t)s0 * 256 + lane * 4];
        v1.u = *(const uint2*)&hp[(size_t)s1 * 256 + lane * 4];
        v2.u = *(const uint2*)&hp[(size_t)s2 * 256 + lane * 4];
        v3.u = *(const uint2*)&hp[(size_t)s3 * 256 + lane * 4];
        e0 = (e0 >= 0.f) ? e0 : NEG_SLOPE * e0;
        e1 = (e1 >= 0.f) ? e1 : NEG_SLOPE * e1;
        e2 = (e2 >= 0.f) ? e2 : NEG_SLOPE * e2;
        e3 = (e3 >= 0.f) ? e3 : NEG_SLOPE * e3;
        float nm = fmaxf(m, fmaxf(fmaxf(e0, e1), fmaxf(e2, e3)));
        float sc = __expf(m - nm);
        float w0 = __expf(e0 - nm), w1 = __expf(e1 - nm);
        float w2 = __expf(e2 - nm), w3 = __expf(e3 - nm);
        s = s * sc + ((w0 + w1) + (w2 + w3));
        a0 = a0 * sc + w0 * (float)v0.q[0] + w1 * (float)v1.q[0] + w2 * (float)v2.q[0] + w3 * (float)v3.q[0];
        a1 = a1 * sc + w0 * (float)v0.q[1] + w1 * (float)v1.q[1] + w2 * (float)v2.q[1] + w3 * (float)v3.q[1];
        a2 = a2 * sc + w0 * (float)v0.q[2] + w1 * (float)v1.q[2] + w2 * (float)v2.q[2] + w3 * (float)v3.q[2];
        a3 = a3 * sc + w0 * (float)v0.q[3] + w1 * (float)v1.q[3] + w2 * (float)v2.q[3] + w3 * (float)v3.q[3];
        m = nm;
    }
    for (; j < end; ++j) {
        int src = sorted_src[j];
        float e = a_s[src * 8 + h] + ad + (float)e_l[(size_t)j * 8 + h];
        e = (e >= 0.f) ? e : NEG_SLOPE * e;
        float nm = fmaxf(m, e);
        float sc = __expf(m - nm);
        float w = __expf(e - nm);
        union { uint2 u; _Float16 q[4]; } hv;
        hv.u = *(const uint2*)&hp[(size_t)src * 256 + lane * 4];
        s = s * sc + w;
        a0 = a0 * sc + w * (float)hv.q[0];
        a1 = a1 * sc + w * (float)hv.q[1];
        a2 = a2 * sc + w * (float)hv.q[2];
        a3 = a3 * sc + w * (float)hv.q[3];
        m = nm;
    }
    float inv = 1.0f / (s + 1e-16f);
    float4 b4 = *(const float4*)&bias[lane * 4];
    float o[4] = {a0 * inv + b4.x, a1 * inv + b4.y, a2 * inv + b4.z, a3 * inv + b4.w};
    ushort4 vhi, vlo;
    ushort* ph = (ushort*)&vhi;
    ushort* pl = (ushort*)&vlo;
#pragma unroll
    for (int c = 0; c < 4; ++c) {
        union { float f; uint u; } uv; uv.f = o[c];
        ph[c] = (ushort)(uv.u >> 16);
        pl[c] = f2bf_rn(o[c] - bf2f(ph[c]));
    }
    *(ushort4*)&h_hi[(size_t)n * 256 + lane * 4] = vhi;
    *(ushort4*)&h_lo[(size_t)n * 256 + lane * 4] = vlo;
}

__global__ __launch_bounds__(256) void out_kernel(const ushort* __restrict__ h_hi,
                                                  const ushort* __restrict__ h_lo,
                                                  const float* __restrict__ w_out,
                                                  const float* __restrict__ b_out,
                                                  float* __restrict__ out) {
    int n = (blockIdx.x * 256 + threadIdx.x) >> 6;
    if (n >= NN) return;
    int lane = threadIdx.x & 63;
    union { uint2 u; ushort s[4]; } uh, ul;
    uh.u = *(const uint2*)&h_hi[(size_t)n * 256 + lane * 4];
    ul.u = *(const uint2*)&h_lo[(size_t)n * 256 + lane * 4];
    const float4 wv = *(const float4*)&w_out[lane * 4];
    float s = (bf2f(uh.s[0]) + bf2f(ul.s[0])) * wv.x +
              (bf2f(uh.s[1]) + bf2f(ul.s[1])) * wv.y +
              (bf2f(uh.s[2]) + bf2f(ul.s[2])) * wv.z +
              (bf2f(uh.s[3]) + bf2f(ul.s[3])) * wv.w;
    for (int off = 1; off < 64; off <<= 1) s += __shfl_xor(s, off);
    if (lane == 0) out[n] = s + b_out[0];
}

// ---------------- launch ----------------

extern "C" void kernel_launch(void* const* d_in, const int* in_sizes, int n_in,
                              void* d_out, int out_size, void* d_ws, size_t ws_size,
                              hipStream_t stream) {
    const float* x         = (const float*)d_in[0];
    const int*   edge_idx  = (const int*)d_in[1];
    const float* edge_attr = (const float*)d_in[2];
    const float* w_in      = (const float*)d_in[3];
    const float* b_in      = (const float*)d_in[4];
    const float* W_l       = (const float*)d_in[5];
    const float* We_l      = (const float*)d_in[6];
    const float* att_src   = (const float*)d_in[7];
    const float* att_dst   = (const float*)d_in[8];
    const float* att_edge  = (const float*)d_in[9];
    const float* bias_l    = (const float*)d_in[10];
    const float* w_out     = (const float*)d_in[11];
    const float* b_out     = (const float*)d_in[12];
    float* out = (float*)d_out;

    char* ws = (char*)d_ws;
    size_t off = 0;
    auto alloc = [&](size_t bytes) -> void* {
        void* p = ws + off;
        off = (off + bytes + 255) & ~(size_t)255;
        return p;
    };
    ushort*   h_hi       = (ushort*)alloc((size_t)MPAD * 256 * 2);
    ushort*   h_lo       = (ushort*)alloc((size_t)MPAD * 256 * 2);
    _Float16* hp16       = (_Float16*)alloc((size_t)MPAD * 256 * 2);
    float*    a_s        = (float*)alloc((size_t)NN * 8 * 4);
    float*    a_d        = (float*)alloc((size_t)NN * 8 * 4);
    int*      sorted_src = (int*)alloc((size_t)ETOT * 4);
    int*      sorted_eid = (int*)alloc((size_t)ETOT * 4);
    int*      row_ptr    = (int*)alloc((size_t)(NN + 1) * 4);
    int*      fill       = (int*)alloc((size_t)NN * 4);
    int*      cnt        = (int*)alloc((size_t)NN * 4);
    int*      bsum       = (int*)alloc(64 * 4);
    float*    mean_accum = (float*)alloc(32 * 4);
    float*    mean_ea    = (float*)alloc(32 * 4);
    float*    v          = (float*)alloc(1024 * 4);
    ushort*   bsp_hi     = (ushort*)alloc((size_t)294912 * 2);
    ushort*   bsp_lo     = (ushort*)alloc((size_t)294912 * 2);
    // union region: {xh, xl} then (after input GEMM) e_all overlays it
    char*     uni        = (char*)alloc((size_t)4 * ETOT * 8 * 2);  // 54.4 MB
    ushort*   xh         = (ushort*)uni;
    ushort*   xl         = (ushort*)(uni + (size_t)MPAD * 128 * 2);
    _Float16* e_all      = (_Float16*)uni;

    const int NB = (NN + 1023) / 1024;  // 49

    // weight prep + input projection (uses xh/xl before e_all overlays)
    zero_int_kernel<<<(NN + 255) / 256, 256, 0, stream>>>(cnt, NN);
    zero_int_kernel<<<1, 256, 0, stream>>>((int*)mean_accum, 32);
    mean_kernel<<<512, 256, 0, stream>>>(edge_attr, mean_accum);
    precompute_kernel<<<1, 1024, 0, stream>>>(mean_accum, We_l, att_edge, mean_ea, v);
    split_weights<<<(294912 + 255) / 256, 256, 0, stream>>>(w_in, W_l, bsp_hi, bsp_lo);
    split_x<<<(MPAD * 128 + 255) / 256, 256, 0, stream>>>(x, xh, xl);

    dim3 ggrid((NN + 127) / 128, 2);
    gemm_mfma<0><<<ggrid, 256, 0, stream>>>(xh, xl, bsp_hi, bsp_lo, b_in,
                                            nullptr, h_hi, h_lo, NN, IN_DIM);

    // graph build + all-layer edge logits (e_all overlays xh/xl — input GEMM done)
    hist_kernel<<<(ETOT + 255) / 256, 256, 0, stream>>>(edge_idx, cnt);
    scan_phase1<<<NB, 256, 0, stream>>>(cnt, bsum);
    scan_phase2<<<1, 64, 0, stream>>>(bsum, row_ptr, NB);
    scan_phase3<<<NB, 256, 0, stream>>>(cnt, bsum, row_ptr, fill);
    scatter_kernel<<<(ETOT + 255) / 256, 256, 0, stream>>>(edge_idx, fill, sorted_src, sorted_eid);
    edge_logits<<<(ETOT + 255) / 256, 256, 0, stream>>>(edge_attr, mean_ea, sorted_eid, v, e_all);

    for (int l = 0; l < LL; ++l) {
        const ushort* wh = bsp_hi + 32768 + (size_t)l * 65536;
        const ushort* wl = bsp_lo + 32768 + (size_t)l * 65536;
        gemm_mfma<1><<<ggrid, 256, 0, stream>>>(h_hi, h_lo, wh, wl, nullptr,
                                                hp16, nullptr, nullptr, NN, EMB);
        a_sd_kernel<<<(NN * 8 + 255) / 256, 256, 0, stream>>>(
            hp16, att_src + l * 256, att_dst + l * 256, a_s, a_d);
        aggregate_kernel<<<NN / 4, 256, 0, stream>>>(
            hp16, a_s, a_d, e_all + (size_t)l * ETOT * 8, sorted_src, row_ptr,
            bias_l + l * 256, h_hi, h_lo);
    }

    out_kernel<<<NN / 4, 256, 0, stream>>>(h_hi, h_lo, w_out, b_out, out);
}